// Round 14
// baseline (4862.175 us; speedup 1.0000x reference)
//
#include <hip/hip_runtime.h>
#include <hip/hip_fp16.h>

// 2-layer LSTM B=256 T=512 I=32 H=256.  r12 structure (1486us proven) +
// per-wave direct partner-fragment loads overlapped with local compute.
// 16 groups x 16 batches x 6 wgs (512 thr): L0a/L0b (Whh0 halves, recurrence
// pair), W1a/W1b (Wih1 halves, h0->xg1), L1a/L1b (Whh1 halves + output).
// All cross-wg transport: MALL (sc0 sc1) rings, fp16-LSB lap tags.
// Change vs r12: pair exchange no longer staged via LDS; each wave issues its
// own 4 partner A-frags (64B/lane) BEFORE the barrier, computes local-half
// MFMAs from LDS, then tag-spins the registers (usually already arrived).
// Pair skew <=1 invariant unchanged (spin still gates every step).
// Fallback: r9 kernel (1580us proven) when ws too small.

#define TT 512
#define HH 256
#define GS 294912   // per-group ws: 128K h0 stream + 16K h1r + 128K xg + prog

typedef _Float16 f16x8 __attribute__((ext_vector_type(8)));
typedef float    f32x4 __attribute__((ext_vector_type(4)));
typedef unsigned u32x4 __attribute__((ext_vector_type(4)));

__device__ __forceinline__ f16x8 cvt8(const float* p) {
  const float4 a = *(const float4*)p;
  const float4 b = *(const float4*)(p + 4);
  f16x8 r;
  r[0]=(_Float16)a.x; r[1]=(_Float16)a.y; r[2]=(_Float16)a.z; r[3]=(_Float16)a.w;
  r[4]=(_Float16)b.x; r[5]=(_Float16)b.y; r[6]=(_Float16)b.z; r[7]=(_Float16)b.w;
  return r;
}
__device__ __forceinline__ float sigm(float x){ return 1.f/(1.f + __expf(-x)); }
__device__ __forceinline__ float tanh_(float x){ return 1.f - 2.f/(1.f + __expf(2.f*x)); }

// ---- MALL-coherent (L2-bypass) primitives, per-lane 64b addressing ----
__device__ __forceinline__ u32x4 ld16(const void* p) {
  u32x4 r;
  asm volatile("global_load_dwordx4 %0, %1, off sc0 sc1"
               : "=v"(r) : "v"(p) : "memory");
  return r;
}
__device__ __forceinline__ void st2(void* p, unsigned v) {
  asm volatile("global_store_short %0, %1, off sc0 sc1"
               :: "v"(p), "v"(v) : "memory");
}
__device__ __forceinline__ void stp(void* p, unsigned v) {
  asm volatile("global_store_dword %0, %1, off sc0 sc1"
               :: "v"(p), "v"(v) : "memory");
}
__device__ __forceinline__ unsigned ldp(const void* p) {
  unsigned r;
  asm volatile("global_load_dword %0, %1, off sc0 sc1\n\ts_waitcnt vmcnt(0)"
               : "=v"(r) : "v"(p) : "memory");
  return r;
}
__device__ __forceinline__ void wvm0() {
  asm volatile("s_waitcnt vmcnt(0)" ::: "memory");
  __builtin_amdgcn_sched_barrier(0);
}
__device__ __forceinline__ void barrier_lds() {
  __builtin_amdgcn_sched_barrier(0);
  asm volatile("s_waitcnt lgkmcnt(0)" ::: "memory");
  __builtin_amdgcn_s_barrier();
  __builtin_amdgcn_sched_barrier(0);
}

__global__ void init_ws(uint4* p, int n) {
  int i = blockIdx.x * blockDim.x + threadIdx.x;
  if (i >= n) return;
  int rem = i % (GS / 16);
  p[i] = (rem < 17408) ? make_uint4(0x00010001u,0x00010001u,0x00010001u,0x00010001u)
                       : make_uint4(0u,0u,0u,0u);   // prog dwords = 0
}

__global__ __launch_bounds__(512) void lstm_v14(
    const float* __restrict__ M,
    const float* __restrict__ Wih0, const float* __restrict__ Whh0,
    const float* __restrict__ bih0, const float* __restrict__ bhh0,
    const float* __restrict__ Wih1, const float* __restrict__ Whh1,
    const float* __restrict__ bih1, const float* __restrict__ bhh1,
    float* __restrict__ out, char* __restrict__ ws)
{
  __shared__ __align__(16) char ldsH[16384];   // 2-parity local-half A-frag h
  __shared__ __align__(16) char ldsX[32768];   // L1: xg dbuf; W1: staged h0 dbuf

  const int tid  = threadIdx.x, lane = tid & 63, wv = tid >> 6;   // 8 waves
  const int bid  = blockIdx.x;
  const int g    = bid / 6;
  const int r6   = bid - g * 6;
  const int role = r6 >> 1;            // 0:L0 1:W1 2:L1
  const int half = r6 & 1;
  const int col16 = lane & 15, ko8 = (lane >> 4) << 3, brow = (lane >> 4) << 2;
  const int unit = half * 128 + wv * 16 + col16;

  char* base   = ws + (size_t)g * GS;
  char* stream = base;                 // 16 slots x 8KB, A-frag layout
  char* h1r    = base + 131072;        // 2 parity slots x 8KB, A-frag layout
  char* xg     = base + 147456;        // 4 slots x [2 half x 16KB]
  int*  prog   = (int*)(base + 278528);   // [0]=W1a [1]=W1b [2]=L1a [3]=L1b

  // A-frag byte position of (batch b, unit u): ubase|(b<<4)  [r10-validated]
  const unsigned ubase = ((unsigned)(unit >> 5) << 10)
                       | ((unsigned)((unit >> 3) & 3) << 8)
                       | ((unsigned)(unit & 7) << 1);
  const unsigned pb = (unsigned)(half ^ 1) * 4096;   // partner ktile region
  const int lk = half * 4;             // local ktile base
  const int pk = (half ^ 1) * 4;       // partner ktile base

  // ---- register-resident weights: 4 gates x 16 units (this wave) ----
  f16x8 W[4][8], WI[4];
  float bias[4] = {0.f, 0.f, 0.f, 0.f};
  {
    const float* Wsrc = (role == 0) ? Whh0 : (role == 1) ? Wih1 : Whh1;
    #pragma unroll
    for (int q = 0; q < 4; ++q) {
      const int row = q * HH + unit;
      #pragma unroll
      for (int kt = 0; kt < 8; ++kt)
        W[q][kt] = cvt8(Wsrc + (size_t)row * HH + kt * 32 + ko8);
      if (role == 0) { WI[q] = cvt8(Wih0 + (size_t)row * 32 + ko8);
                       bias[q] = bih0[row] + bhh0[row]; }
      else if (role == 1) bias[q] = bih1[row] + bhh1[row];
    }
  }

  float cst[4] = {0.f, 0.f, 0.f, 0.f};

  if (role == 0) {
    // =================== L0 pair: latency-critical recurrence ===================
    const float* mp = M + (size_t)(g * 16 + col16) * TT * 32 + ko8;
    float4 m0 = *(const float4*)mp, m1 = *(const float4*)(mp + 4);
    int lastW = 0;
    for (int t = 0; t < TT; ++t) {
      const int rpar = (t - 1) & 1;
      u32x4 pf[4];
      if (t >= 1) {                    // issue own partner frags EARLY
        const char* a = stream + (size_t)((t - 1) & 15) * 8192 + pb + lane * 16;
        #pragma unroll
        for (int i = 0; i < 4; ++i) pf[i] = ld16(a + i * 1024);
      }
      barrier_lds();                   // tail LDS writes of t-1 -> readable
      if (t >= 16) {                   // slot overwrite throttle vs W1 pair
        while (lastW < t - 15) {
          const int a = (int)ldp(prog + 0), b = (int)ldp(prog + 1);
          lastW = a < b ? a : b;
        }
      }
      f32x4 acc[4];
      f16x8 am;
      am[0]=(_Float16)m0.x; am[1]=(_Float16)m0.y; am[2]=(_Float16)m0.z; am[3]=(_Float16)m0.w;
      am[4]=(_Float16)m1.x; am[5]=(_Float16)m1.y; am[6]=(_Float16)m1.z; am[7]=(_Float16)m1.w;
      #pragma unroll
      for (int q = 0; q < 4; ++q) {
        acc[q] = (f32x4){bias[q], bias[q], bias[q], bias[q]};
        acc[q] = __builtin_amdgcn_mfma_f32_16x16x32_f16(am, WI[q], acc[q], 0, 0, 0);
      }
      if (t >= 1) {
        #pragma unroll
        for (int i = 0; i < 4; ++i) {  // local-half ktiles (LDS, no RTT)
          const f16x8 A = *(const f16x8*)(ldsH + rpar * 8192 + (lk + i) * 1024 + lane * 16);
          #pragma unroll
          for (int q = 0; q < 4; ++q)
            acc[q] = __builtin_amdgcn_mfma_f32_16x16x32_f16(A, W[q][lk + i], acc[q], 0, 0, 0);
        }
        // partner spin (loads issued pre-barrier; usually already arrived)
        const unsigned pat = (((unsigned)(t - 1) >> 4) & 1u) * 0x00010001u;
        const char* a = stream + (size_t)((t - 1) & 15) * 8192 + pb + lane * 16;
        wvm0();
        for (;;) {
          unsigned bad = 0;
          #pragma unroll
          for (int i = 0; i < 4; ++i) {
            const u32x4 d = (pf[i] ^ pat) & 0x00010001u;
            bad |= d[0] | d[1] | d[2] | d[3];
          }
          if (__all(bad == 0)) break;
          #pragma unroll
          for (int i = 0; i < 4; ++i) pf[i] = ld16(a + i * 1024);
          wvm0();
        }
        #pragma unroll
        for (int i = 0; i < 4; ++i) {  // partner ktiles from registers
          const f16x8 A = __builtin_bit_cast(f16x8, pf[i]);
          #pragma unroll
          for (int q = 0; q < 4; ++q)
            acc[q] = __builtin_amdgcn_mfma_f32_16x16x32_f16(A, W[q][pk + i], acc[q], 0, 0, 0);
        }
      }
      if (t + 1 < TT) { m0 = *(const float4*)(mp + (t + 1) * 32);
                        m1 = *(const float4*)(mp + (t + 1) * 32 + 4); }
      char* slot = stream + (size_t)(t & 15) * 8192;
      const unsigned wt = ((unsigned)t >> 4) & 1u;
      #pragma unroll
      for (int r = 0; r < 4; ++r) {
        const float iv = sigm(acc[0][r]), fv = sigm(acc[1][r]);
        const float gv = tanh_(acc[2][r]), ov = sigm(acc[3][r]);
        cst[r] = fv * cst[r] + iv * gv;
        const float h = ov * tanh_(cst[r]);
        unsigned short hb = __builtin_bit_cast(unsigned short, (_Float16)h);
        hb = (unsigned short)((hb & 0xFFFEu) | wt);
        const unsigned fo = ubase + ((unsigned)(brow + r) << 4);
        st2(slot + fo, (unsigned)hb);                         // fire-and-forget
        *(unsigned short*)(ldsH + (t & 1) * 8192 + fo) = hb;  // local half only
      }
    }
  } else if (role == 1) {
    // =================== W1 pair: Wih1*h0 -> xg1 stream (slack) ===================
    int lastL = 0;
    for (int t = 0; t < TT; ++t) {
      const char* a = stream + (size_t)(t & 15) * 8192 + tid * 16;
      const unsigned pat = (((unsigned)t >> 4) & 1u) * 0x00010001u;
      u32x4 v = ld16(a);                     // stage full h0[t] (8KB)
      wvm0();
      for (;;) {
        const u32x4 d = (v ^ pat) & 0x00010001u;
        if (__all((d[0] | d[1] | d[2] | d[3]) == 0)) break;
        v = ld16(a);
        wvm0();
      }
      *(u32x4*)(ldsX + (t & 1) * 8192 + tid * 16) = v;
      barrier_lds();
      if (tid == 0) stp(prog + half, (unsigned)(t + 1));
      if (t >= 4) { while (lastL < t - 3) lastL = (int)ldp(prog + 2 + half); }
      f32x4 acc[4];
      #pragma unroll
      for (int q = 0; q < 4; ++q)
        acc[q] = (f32x4){bias[q], bias[q], bias[q], bias[q]};
      #pragma unroll
      for (int kt = 0; kt < 8; ++kt) {
        const f16x8 A = *(const f16x8*)(ldsX + (t & 1) * 8192 + kt * 1024 + lane * 16);
        #pragma unroll
        for (int q = 0; q < 4; ++q)
          acc[q] = __builtin_amdgcn_mfma_f32_16x16x32_f16(A, W[q][kt], acc[q], 0, 0, 0);
      }
      char* xs = xg + (size_t)(t & 3) * 32768 + half * 16384;
      const unsigned wtx = ((unsigned)t >> 2) & 1u;
      #pragma unroll
      for (int q = 0; q < 4; ++q)
        #pragma unroll
        for (int r = 0; r < 4; ++r) {
          unsigned short hb = __builtin_bit_cast(unsigned short, (_Float16)acc[q][r]);
          hb = (unsigned short)((hb & 0xFFFEu) | wtx);
          const unsigned off = (unsigned)(brow + r) * 1024
                             + (unsigned)(q * 128 + wv * 16 + col16) * 2;
          st2(xs + off, (unsigned)hb);
        }
    }
  } else {
    // =================== L1 pair: recurrence + xg1 add + output ===================
    for (int t = 0; t < TT; ++t) {
      const int rpar = (t - 1) & 1;
      u32x4 pf[4];
      const char* pa = h1r + (size_t)rpar * 8192 + pb + lane * 16;
      if (t >= 1) {                    // issue own partner h1 frags EARLY
        #pragma unroll
        for (int i = 0; i < 4; ++i) pf[i] = ld16(pa + i * 1024);
      }
      // xg staging (slack ring, usually ready)
      const char* sx = xg + (size_t)(t & 3) * 32768 + half * 16384;
      const unsigned patX = (((unsigned)t >> 2) & 1u) * 0x00010001u;
      u32x4 x0 = ld16(sx + tid * 32), x1 = ld16(sx + tid * 32 + 16);
      wvm0();
      for (;;) {
        const u32x4 d = ((x0 ^ patX) | (x1 ^ patX)) & 0x00010001u;
        if (__all((d[0] | d[1] | d[2] | d[3]) == 0)) break;
        x0 = ld16(sx + tid * 32); x1 = ld16(sx + tid * 32 + 16);
        wvm0();
      }
      *(u32x4*)(ldsX + (t & 1) * 16384 + tid * 32)      = x0;
      *(u32x4*)(ldsX + (t & 1) * 16384 + tid * 32 + 16) = x1;
      barrier_lds();
      if (tid == 0) stp(prog + 2 + half, (unsigned)(t + 1));
      f32x4 acc[4];
      #pragma unroll
      for (int q = 0; q < 4; ++q) acc[q] = (f32x4){0.f, 0.f, 0.f, 0.f};
      if (t >= 1) {
        #pragma unroll
        for (int i = 0; i < 4; ++i) {  // local-half h1 ktiles (LDS)
          const f16x8 A = *(const f16x8*)(ldsH + rpar * 8192 + (lk + i) * 1024 + lane * 16);
          #pragma unroll
          for (int q = 0; q < 4; ++q)
            acc[q] = __builtin_amdgcn_mfma_f32_16x16x32_f16(A, W[q][lk + i], acc[q], 0, 0, 0);
        }
        // partner h1 spin (issued pre-stage; likely arrived)
        const unsigned patA = (((unsigned)(t - 1) >> 1) & 1u) * 0x00010001u;
        for (;;) {
          unsigned bad = 0;
          #pragma unroll
          for (int i = 0; i < 4; ++i) {
            const u32x4 d = (pf[i] ^ patA) & 0x00010001u;
            bad |= d[0] | d[1] | d[2] | d[3];
          }
          if (__all(bad == 0)) break;
          #pragma unroll
          for (int i = 0; i < 4; ++i) pf[i] = ld16(pa + i * 1024);
          wvm0();
        }
        #pragma unroll
        for (int i = 0; i < 4; ++i) {  // partner ktiles from registers
          const f16x8 A = __builtin_bit_cast(f16x8, pf[i]);
          #pragma unroll
          for (int q = 0; q < 4; ++q)
            acc[q] = __builtin_amdgcn_mfma_f32_16x16x32_f16(A, W[q][pk + i], acc[q], 0, 0, 0);
        }
      }
      const char* xl = ldsX + (t & 1) * 16384;
      #pragma unroll
      for (int q = 0; q < 4; ++q)
        #pragma unroll
        for (int r = 0; r < 4; ++r) {
          const unsigned short xv = *(const unsigned short*)
            (xl + (brow + r) * 1024 + (q * 128 + wv * 16 + col16) * 2);
          acc[q][r] += (float)__builtin_bit_cast(_Float16, xv);
        }
      char* d1 = h1r + (size_t)(t & 1) * 8192;
      const unsigned wt = ((unsigned)t >> 1) & 1u;
      #pragma unroll
      for (int r = 0; r < 4; ++r) {
        const float iv = sigm(acc[0][r]), fv = sigm(acc[1][r]);
        const float gv = tanh_(acc[2][r]), ov = sigm(acc[3][r]);
        cst[r] = fv * cst[r] + iv * gv;
        const float h = ov * tanh_(cst[r]);
        if (t < TT - 1) {
          unsigned short hb = __builtin_bit_cast(unsigned short, (_Float16)h);
          hb = (unsigned short)((hb & 0xFFFEu) | wt);
          const unsigned fo = ubase + ((unsigned)(brow + r) << 4);
          st2(d1 + fo, (unsigned)hb);
          *(unsigned short*)(ldsH + (t & 1) * 8192 + fo) = hb;
        } else {
          out[(size_t)(g * 16 + brow + r) * HH + unit] = h;
        }
      }
    }
  }
}

// ================= fallback: round-9 kernel (1580us proven) =================
__global__ void fb_init(uint4* p, int n) {
  int i = blockIdx.x * blockDim.x + threadIdx.x;
  if (i < n) p[i] = make_uint4(0x00010001u,0x00010001u,0x00010001u,0x00010001u);
}
__device__ __forceinline__ unsigned fb_tg(int t){ return ((unsigned)(t + 4) >> 1) & 1u; }

__global__ __launch_bounds__(512) void lstm_v9(
    const float* __restrict__ M,
    const float* __restrict__ Wih0, const float* __restrict__ Whh0,
    const float* __restrict__ bih0, const float* __restrict__ bhh0,
    const float* __restrict__ Wih1, const float* __restrict__ Whh1,
    const float* __restrict__ bih1, const float* __restrict__ bhh1,
    float* __restrict__ out, char* __restrict__ ws)
{
  __shared__ __align__(16) char  ldsA[16384];
  __shared__ __align__(16) f32x4 xch[8][64];
  const int tid  = threadIdx.x, lane = tid & 63, wv = tid >> 6;
  const int g = blockIdx.x & 7, w = blockIdx.x >> 3;
  const int hf = wv & 1, role = wv >> 1;
  const int col16 = lane & 15, ko8 = (lane >> 4) << 3;
  const int unit = w * 16 + col16;
  #define H0R(slot) (ws + (((g << 1) | (slot)) << 14))
  #define H1R(slot) (ws + 262144 + (((g << 1) | (slot)) << 14))
  f16x8 W0[4][8], WI[4];
  float bias[4] = {0.f, 0.f, 0.f, 0.f};
  if (role == 0) {
    #pragma unroll
    for (int q = 0; q < 4; ++q) {
      const int row = q * HH + unit;
      #pragma unroll
      for (int kt = 0; kt < 8; ++kt) W0[q][kt] = cvt8(Whh0 + (size_t)row*HH + kt*32 + ko8);
      WI[q] = cvt8(Wih0 + (size_t)row*32 + ko8); bias[q] = bih0[row] + bhh0[row];
    }
  } else if (role == 1) {
    #pragma unroll
    for (int q = 0; q < 4; ++q) {
      const int row = q * HH + unit;
      #pragma unroll
      for (int kt = 0; kt < 8; ++kt) W0[q][kt] = cvt8(Wih1 + (size_t)row*HH + kt*32 + ko8);
      bias[q] = bih1[row] + bhh1[row];
    }
  } else if (role == 2) {
    #pragma unroll
    for (int q = 0; q < 4; ++q) {
      const int row = q * HH + unit;
      #pragma unroll
      for (int kt = 0; kt < 8; ++kt) W0[q][kt] = cvt8(Whh1 + (size_t)row*HH + kt*32 + ko8);
    }
  }
  const int sl = tid & 63, skt = (tid >> 6) & 7;
  const unsigned moff0 = (unsigned)((sl & 15) * 512 + skt * 64 + (sl >> 4) * 16);
  const unsigned moff1 = moff0 + 16 * 512;
  const unsigned lo    = (unsigned)(skt * 1024 + sl * 16);
  const unsigned hoff = (((unsigned)(hf*16 + col16)) << 9) | ((unsigned)(lane >> 4) << 4);
  unsigned soff[4];
  #pragma unroll
  for (int r = 0; r < 4; ++r)
    soff[r] = (((unsigned)(hf*16 + ((lane>>4)<<2) + r)) << 9) | ((unsigned)unit << 1);
  const float* mp = M + (size_t)(g*32 + hf*16 + col16) * TT * 32 + ko8;
  float4 m0 = {0,0,0,0}, m1 = {0,0,0,0};
  if (role == 0) { m0 = *(const float4*)mp; m1 = *(const float4*)(mp + 4); }
  float cst[4] = {0.f, 0.f, 0.f, 0.f};
  for (int p = 0; p <= TT; ++p) {
    if (p >= 1) {
      const char* s = H0R((p - 1) & 1);
      const unsigned pat = fb_tg(p - 1) * 0x00010001u;
      u32x4 v0 = ld16(s + moff0), v1 = ld16(s + moff1);
      wvm0();
      for (;;) {
        const u32x4 d = ((v0 ^ pat) | (v1 ^ pat)) & 0x00010001u;
        if (__all((d[0] | d[1] | d[2] | d[3]) == 0)) break;
        v0 = ld16(s + moff0); v1 = ld16(s + moff1); wvm0();
      }
      *(u32x4*)(ldsA + lo) = v0; *(u32x4*)(ldsA + 8192 + lo) = v1;
    }
    barrier_lds();
    f32x4 acc[4];
    if (role == 0 && p < TT) {
      f16x8 am;
      am[0]=(_Float16)m0.x; am[1]=(_Float16)m0.y; am[2]=(_Float16)m0.z; am[3]=(_Float16)m0.w;
      am[4]=(_Float16)m1.x; am[5]=(_Float16)m1.y; am[6]=(_Float16)m1.z; am[7]=(_Float16)m1.w;
      #pragma unroll
      for (int q = 0; q < 4; ++q) {
        acc[q] = (f32x4){bias[q], bias[q], bias[q], bias[q]};
        acc[q] = __builtin_amdgcn_mfma_f32_16x16x32_f16(am, WI[q], acc[q], 0, 0, 0);
      }
      if (p >= 1) {
        #pragma unroll
        for (int kt = 0; kt < 8; ++kt) {
          const f16x8 A = *(const f16x8*)(ldsA + hf*8192 + kt*1024 + lane*16);
          #pragma unroll
          for (int q = 0; q < 4; ++q)
            acc[q] = __builtin_amdgcn_mfma_f32_16x16x32_f16(A, W0[q][kt], acc[q], 0, 0, 0);
        }
      }
      char* d = H0R(p & 1);
      const unsigned wt = fb_tg(p);
      #pragma unroll
      for (int r = 0; r < 4; ++r) {
        const float iv = sigm(acc[0][r]), fv = sigm(acc[1][r]);
        const float gv = tanh_(acc[2][r]), ov = sigm(acc[3][r]);
        cst[r] = fv * cst[r] + iv * gv;
        const float h = ov * tanh_(cst[r]);
        unsigned short hb = __builtin_bit_cast(unsigned short, (_Float16)h);
        hb = (unsigned short)((hb & 0xFFFEu) | wt);
        st2(d + soff[r], (unsigned)hb);
      }
      if (p + 1 < TT) { m0 = *(const float4*)(mp + (p+1)*32); m1 = *(const float4*)(mp + (p+1)*32 + 4); }
    } else if (role == 1 && p >= 1) {
      #pragma unroll
      for (int q = 0; q < 4; ++q) acc[q] = (f32x4){bias[q], bias[q], bias[q], bias[q]};
      #pragma unroll
      for (int kt = 0; kt < 8; ++kt) {
        const f16x8 A = *(const f16x8*)(ldsA + hf*8192 + kt*1024 + lane*16);
        #pragma unroll
        for (int q = 0; q < 4; ++q)
          acc[q] = __builtin_amdgcn_mfma_f32_16x16x32_f16(A, W0[q][kt], acc[q], 0, 0, 0);
      }
    } else if (role == 2 && p >= 2) {
      const char* s = H1R(p & 1);
      const unsigned pat = fb_tg(p - 2) * 0x00010001u;
      u32x4 hb[8];
      #pragma unroll
      for (int k = 0; k < 8; ++k) hb[k] = ld16(s + hoff + k*64);
      wvm0();
      for (;;) {
        unsigned bad = 0;
        #pragma unroll
        for (int k = 0; k < 8; ++k) {
          const u32x4 d = (hb[k] ^ pat) & 0x00010001u;
          bad |= d[0] | d[1] | d[2] | d[3];
        }
        if (__all(bad == 0)) break;
        #pragma unroll
        for (int k = 0; k < 8; ++k) hb[k] = ld16(s + hoff + k*64);
        wvm0();
      }
      #pragma unroll
      for (int q = 0; q < 4; ++q) acc[q] = (f32x4){0.f, 0.f, 0.f, 0.f};
      #pragma unroll
      for (int kt = 0; kt < 8; ++kt) {
        const f16x8 A = __builtin_bit_cast(f16x8, hb[kt]);
        #pragma unroll
        for (int q = 0; q < 4; ++q)
          acc[q] = __builtin_amdgcn_mfma_f32_16x16x32_f16(A, W0[q][kt], acc[q], 0, 0, 0);
      }
      #pragma unroll
      for (int q = 0; q < 4; ++q) xch[hf*4 + q][lane] = acc[q];
    }
    barrier_lds();
    if (role == 1 && p >= 1) {
      if (p >= 2) {
        #pragma unroll
        for (int q = 0; q < 4; ++q) acc[q] = acc[q] + xch[hf*4 + q][lane];
      }
      if (p < TT) {
        char* d = H1R((p - 1) & 1);
        const unsigned wt = fb_tg(p - 1);
        #pragma unroll
        for (int r = 0; r < 4; ++r) {
          const float iv = sigm(acc[0][r]), fv = sigm(acc[1][r]);
          const float gv = tanh_(acc[2][r]), ov = sigm(acc[3][r]);
          cst[r] = fv * cst[r] + iv * gv;
          const float h = ov * tanh_(cst[r]);
          unsigned short hb = __builtin_bit_cast(unsigned short, (_Float16)h);
          hb = (unsigned short)((hb & 0xFFFEu) | wt);
          st2(d + soff[r], (unsigned)hb);
        }
      } else {
        #pragma unroll
        for (int r = 0; r < 4; ++r) {
          const float iv = sigm(acc[0][r]), fv = sigm(acc[1][r]);
          const float gv = tanh_(acc[2][r]), ov = sigm(acc[3][r]);
          cst[r] = fv * cst[r] + iv * gv;
          const float h = ov * tanh_(cst[r]);
          const int b = hf*16 + ((lane>>4)<<2) + r;
          out[(size_t)(g*32 + b) * HH + (w*16 + col16)] = h;
        }
      }
    }
  }
  #undef H0R
  #undef H1R
}

extern "C" void kernel_launch(void* const* d_in, const int* in_sizes, int n_in,
                              void* d_out, int out_size, void* d_ws, size_t ws_size,
                              hipStream_t stream) {
  (void)in_sizes; (void)n_in; (void)out_size;
  const float* M    = (const float*)d_in[0];
  const float* Wih0 = (const float*)d_in[1];
  const float* Whh0 = (const float*)d_in[2];
  const float* bih0 = (const float*)d_in[3];
  const float* bhh0 = (const float*)d_in[4];
  const float* Wih1 = (const float*)d_in[5];
  const float* Whh1 = (const float*)d_in[6];
  const float* bih1 = (const float*)d_in[7];
  const float* bhh1 = (const float*)d_in[8];

  if (ws_size >= (size_t)16 * GS) {
    const int n16 = 16 * (GS / 16);
    init_ws<<<(n16 + 255) / 256, 256, 0, stream>>>((uint4*)d_ws, n16);
    lstm_v14<<<96, 512, 0, stream>>>(M, Wih0, Whh0, bih0, bhh0,
                                     Wih1, Whh1, bih1, bhh1,
                                     (float*)d_out, (char*)d_ws);
  } else {
    if (ws_size < 524288) return;
    fb_init<<<128, 256, 0, stream>>>((uint4*)d_ws, 32768);
    lstm_v9<<<128, 512, 0, stream>>>(M, Wih0, Whh0, bih0, bhh0,
                                     Wih1, Whh1, bih1, bhh1,
                                     (float*)d_out, (char*)d_ws);
  }
}

// Round 15
// 4632.502 us; speedup vs baseline: 1.0496x; 1.0496x over previous
//
#include <hip/hip_runtime.h>
#include <hip/hip_fp16.h>

// 2-layer LSTM B=256 T=512 I=32 H=256.  r12 structure (1486us proven) with:
//  (a) __launch_bounds__(512,1): r12's default capped VGPRs at 128 < the 144+
//      weight fragments => per-step scratch spills in the critical loop.
//      m69: 8 waves/CU still fit at 256 VGPR, so no occupancy loss.
//  (b) cooperative stage loads issued at TOP of step, tag-checked AFTER the
//      independent local compute (WI*M + local-half MFMAs) -- partner store
//      visibility overlaps ~400ns of compute. Staging stays cooperative
//      (single-copy; per-wave spins congest MALL -- r8/r14 lesson).
// Roles per group (16 groups x 16 batches x 6 wgs of 512 thr):
//   L0a/L0b: Whh0 halves, latency-critical recurrence pair.
//   W1a/W1b: Wih1 halves, h0 -> xg1 stream (slack-buffered).
//   L1a/L1b: Whh1 halves, recurrence pair + xg1 add + output.
// Transport: MALL (sc0 sc1) rings, fp16-LSB lap tags, fire-and-forget stores,
// cached-progress throttles. Fallback: r9 kernel (1580us proven).

#define TT 512
#define HH 256
#define GS 294912   // per-group ws: 128K h0 stream + 16K h1r + 128K xg + prog

typedef _Float16 f16x8 __attribute__((ext_vector_type(8)));
typedef float    f32x4 __attribute__((ext_vector_type(4)));
typedef unsigned u32x4 __attribute__((ext_vector_type(4)));

__device__ __forceinline__ f16x8 cvt8(const float* p) {
  const float4 a = *(const float4*)p;
  const float4 b = *(const float4*)(p + 4);
  f16x8 r;
  r[0]=(_Float16)a.x; r[1]=(_Float16)a.y; r[2]=(_Float16)a.z; r[3]=(_Float16)a.w;
  r[4]=(_Float16)b.x; r[5]=(_Float16)b.y; r[6]=(_Float16)b.z; r[7]=(_Float16)b.w;
  return r;
}
__device__ __forceinline__ float sigm(float x){ return 1.f/(1.f + __expf(-x)); }
__device__ __forceinline__ float tanh_(float x){ return 1.f - 2.f/(1.f + __expf(2.f*x)); }

// ---- MALL-coherent (L2-bypass) primitives, per-lane 64b addressing ----
__device__ __forceinline__ u32x4 ld16(const void* p) {
  u32x4 r;
  asm volatile("global_load_dwordx4 %0, %1, off sc0 sc1"
               : "=v"(r) : "v"(p) : "memory");
  return r;
}
__device__ __forceinline__ void st2(void* p, unsigned v) {
  asm volatile("global_store_short %0, %1, off sc0 sc1"
               :: "v"(p), "v"(v) : "memory");
}
__device__ __forceinline__ void stp(void* p, unsigned v) {
  asm volatile("global_store_dword %0, %1, off sc0 sc1"
               :: "v"(p), "v"(v) : "memory");
}
__device__ __forceinline__ unsigned ldp(const void* p) {
  unsigned r;
  asm volatile("global_load_dword %0, %1, off sc0 sc1\n\ts_waitcnt vmcnt(0)"
               : "=v"(r) : "v"(p) : "memory");
  return r;
}
__device__ __forceinline__ void wvm0() {
  asm volatile("s_waitcnt vmcnt(0)" ::: "memory");
  __builtin_amdgcn_sched_barrier(0);
}
__device__ __forceinline__ void barrier_lds() {
  __builtin_amdgcn_sched_barrier(0);
  asm volatile("s_waitcnt lgkmcnt(0)" ::: "memory");
  __builtin_amdgcn_s_barrier();
  __builtin_amdgcn_sched_barrier(0);
}

__global__ void init_ws(uint4* p, int n) {
  int i = blockIdx.x * blockDim.x + threadIdx.x;
  if (i >= n) return;
  int rem = i % (GS / 16);
  p[i] = (rem < 17408) ? make_uint4(0x00010001u,0x00010001u,0x00010001u,0x00010001u)
                       : make_uint4(0u,0u,0u,0u);   // prog dwords = 0
}

__global__ __launch_bounds__(512, 1) void lstm_v15(
    const float* __restrict__ M,
    const float* __restrict__ Wih0, const float* __restrict__ Whh0,
    const float* __restrict__ bih0, const float* __restrict__ bhh0,
    const float* __restrict__ Wih1, const float* __restrict__ Whh1,
    const float* __restrict__ bih1, const float* __restrict__ bhh1,
    float* __restrict__ out, char* __restrict__ ws)
{
  __shared__ __align__(16) char ldsH[16384];   // 2-parity A-frag h (L0/L1)
  __shared__ __align__(16) char ldsX[32768];   // L1: xg dbuf; W1: staged h0 dbuf

  const int tid  = threadIdx.x, lane = tid & 63, wv = tid >> 6;   // 8 waves
  const int bid  = blockIdx.x;
  const int g    = bid / 6;
  const int r6   = bid - g * 6;
  const int role = r6 >> 1;            // 0:L0 1:W1 2:L1
  const int half = r6 & 1;
  const int col16 = lane & 15, ko8 = (lane >> 4) << 3, brow = (lane >> 4) << 2;
  const int unit = half * 128 + wv * 16 + col16;

  char* base   = ws + (size_t)g * GS;
  char* stream = base;                 // 16 slots x 8KB, A-frag layout
  char* h1r    = base + 131072;        // 2 parity slots x 8KB, A-frag layout
  char* xg     = base + 147456;        // 4 slots x [2 half x 16KB]
  int*  prog   = (int*)(base + 278528);   // [0]=W1a [1]=W1b [2]=L1a [3]=L1b

  const unsigned ubase = ((unsigned)(unit >> 5) << 10)
                       | ((unsigned)((unit >> 3) & 3) << 8)
                       | ((unsigned)(unit & 7) << 1);
  const unsigned pb = (unsigned)(half ^ 1) * 4096;   // partner ktile region
  const int lk = half * 4;             // local ktile base
  const int pk = (half ^ 1) * 4;       // partner ktile base

  // ---- register-resident weights: 4 gates x 16 units (this wave) ----
  f16x8 W[4][8], WI[4];
  float bias[4] = {0.f, 0.f, 0.f, 0.f};
  {
    const float* Wsrc = (role == 0) ? Whh0 : (role == 1) ? Wih1 : Whh1;
    #pragma unroll
    for (int q = 0; q < 4; ++q) {
      const int row = q * HH + unit;
      #pragma unroll
      for (int kt = 0; kt < 8; ++kt)
        W[q][kt] = cvt8(Wsrc + (size_t)row * HH + kt * 32 + ko8);
      if (role == 0) { WI[q] = cvt8(Wih0 + (size_t)row * 32 + ko8);
                       bias[q] = bih0[row] + bhh0[row]; }
      else if (role == 1) bias[q] = bih1[row] + bhh1[row];
    }
  }

  float cst[4] = {0.f, 0.f, 0.f, 0.f};

  if (role == 0) {
    // =================== L0 pair: latency-critical recurrence ===================
    const float* mp = M + (size_t)(g * 16 + col16) * TT * 32 + ko8;
    float4 m0 = *(const float4*)mp, m1 = *(const float4*)(mp + 4);
    int lastW = 0;
    for (int t = 0; t < TT; ++t) {
      const int rpar = (t - 1) & 1;
      barrier_lds();                       // orders prev-step ldsH local writes
      const char* sa = stream + (size_t)((t - 1) & 15) * 8192 + pb + tid * 16;
      const bool stager = (t >= 1) && (tid < 256);
      u32x4 sv;
      if (stager) sv = ld16(sa);           // issue partner-half load EARLY
      // ---- phase A: local compute (no partner dependency) ----
      f32x4 acc[4];
      f16x8 am;
      am[0]=(_Float16)m0.x; am[1]=(_Float16)m0.y; am[2]=(_Float16)m0.z; am[3]=(_Float16)m0.w;
      am[4]=(_Float16)m1.x; am[5]=(_Float16)m1.y; am[6]=(_Float16)m1.z; am[7]=(_Float16)m1.w;
      #pragma unroll
      for (int q = 0; q < 4; ++q) {
        acc[q] = (f32x4){bias[q], bias[q], bias[q], bias[q]};
        acc[q] = __builtin_amdgcn_mfma_f32_16x16x32_f16(am, WI[q], acc[q], 0, 0, 0);
      }
      if (t >= 1) {
        #pragma unroll
        for (int i = 0; i < 4; ++i) {
          const f16x8 A = *(const f16x8*)(ldsH + rpar * 8192 + (lk + i) * 1024 + lane * 16);
          #pragma unroll
          for (int q = 0; q < 4; ++q)
            acc[q] = __builtin_amdgcn_mfma_f32_16x16x32_f16(A, W[q][lk + i], acc[q], 0, 0, 0);
        }
      }
      // ---- phase B: finish cooperative staging (visibility overlapped) ----
      if (stager) {
        const unsigned pat = (((unsigned)(t - 1) >> 4) & 1u) * 0x00010001u;
        wvm0();
        for (;;) {
          const u32x4 d = (sv ^ pat) & 0x00010001u;
          if (__all((d[0] | d[1] | d[2] | d[3]) == 0)) break;
          sv = ld16(sa);
          wvm0();
        }
        *(u32x4*)(ldsH + rpar * 8192 + pb + tid * 16) = sv;
      }
      barrier_lds();
      // ---- phase C: partner MFMAs + elementwise + stores ----
      if (t >= 1) {
        #pragma unroll
        for (int i = 0; i < 4; ++i) {
          const f16x8 A = *(const f16x8*)(ldsH + rpar * 8192 + (pk + i) * 1024 + lane * 16);
          #pragma unroll
          for (int q = 0; q < 4; ++q)
            acc[q] = __builtin_amdgcn_mfma_f32_16x16x32_f16(A, W[q][pk + i], acc[q], 0, 0, 0);
        }
      }
      if (t >= 16) {                       // slot overwrite throttle vs W1 pair
        while (lastW < t - 15) {
          const int a = (int)ldp(prog + 0), b = (int)ldp(prog + 1);
          lastW = a < b ? a : b;
        }
      }
      char* slot = stream + (size_t)(t & 15) * 8192;
      const unsigned wt = ((unsigned)t >> 4) & 1u;
      #pragma unroll
      for (int r = 0; r < 4; ++r) {
        const float iv = sigm(acc[0][r]), fv = sigm(acc[1][r]);
        const float gv = tanh_(acc[2][r]), ov = sigm(acc[3][r]);
        cst[r] = fv * cst[r] + iv * gv;
        const float h = ov * tanh_(cst[r]);
        unsigned short hb = __builtin_bit_cast(unsigned short, (_Float16)h);
        hb = (unsigned short)((hb & 0xFFFEu) | wt);
        const unsigned fo = ubase + ((unsigned)(brow + r) << 4);
        st2(slot + fo, (unsigned)hb);                         // fire-and-forget
        *(unsigned short*)(ldsH + (t & 1) * 8192 + fo) = hb;  // local half only
      }
      if (t + 1 < TT) { m0 = *(const float4*)(mp + (t + 1) * 32);
                        m1 = *(const float4*)(mp + (t + 1) * 32 + 4); }
    }
  } else if (role == 1) {
    // =================== W1 pair: Wih1*h0 -> xg1 stream (r12 verbatim) ===================
    int lastL = 0;
    for (int t = 0; t < TT; ++t) {
      const char* a = stream + (size_t)(t & 15) * 8192 + tid * 16;
      const unsigned pat = (((unsigned)t >> 4) & 1u) * 0x00010001u;
      u32x4 v = ld16(a);                     // stage full h0[t] (8KB)
      wvm0();
      for (;;) {
        const u32x4 d = (v ^ pat) & 0x00010001u;
        if (__all((d[0] | d[1] | d[2] | d[3]) == 0)) break;
        v = ld16(a);
        wvm0();
      }
      *(u32x4*)(ldsX + (t & 1) * 8192 + tid * 16) = v;
      barrier_lds();
      if (tid == 0) stp(prog + half, (unsigned)(t + 1));
      if (t >= 4) { while (lastL < t - 3) lastL = (int)ldp(prog + 2 + half); }
      f32x4 acc[4];
      #pragma unroll
      for (int q = 0; q < 4; ++q)
        acc[q] = (f32x4){bias[q], bias[q], bias[q], bias[q]};
      #pragma unroll
      for (int kt = 0; kt < 8; ++kt) {
        const f16x8 A = *(const f16x8*)(ldsX + (t & 1) * 8192 + kt * 1024 + lane * 16);
        #pragma unroll
        for (int q = 0; q < 4; ++q)
          acc[q] = __builtin_amdgcn_mfma_f32_16x16x32_f16(A, W[q][kt], acc[q], 0, 0, 0);
      }
      char* xs = xg + (size_t)(t & 3) * 32768 + half * 16384;
      const unsigned wtx = ((unsigned)t >> 2) & 1u;
      #pragma unroll
      for (int q = 0; q < 4; ++q)
        #pragma unroll
        for (int r = 0; r < 4; ++r) {
          unsigned short hb = __builtin_bit_cast(unsigned short, (_Float16)acc[q][r]);
          hb = (unsigned short)((hb & 0xFFFEu) | wtx);
          const unsigned off = (unsigned)(brow + r) * 1024
                             + (unsigned)(q * 128 + wv * 16 + col16) * 2;
          st2(xs + off, (unsigned)hb);
        }
    }
  } else {
    // =================== L1 pair: recurrence + xg1 add + output ===================
    for (int t = 0; t < TT; ++t) {
      const int rpar = (t - 1) & 1;
      barrier_lds();                       // orders prev-step ldsH local writes
      const char* sx = xg + (size_t)(t & 3) * 32768 + half * 16384;
      const char* pa = h1r + (size_t)rpar * 8192 + pb + tid * 16;
      const bool hasA = (t >= 1) && (tid < 256);
      u32x4 x0 = ld16(sx + tid * 32), x1 = ld16(sx + tid * 32 + 16), va;
      if (hasA) va = ld16(pa);             // issue EARLY
      // ---- phase A: local-half h1 MFMAs ----
      f32x4 acc[4];
      #pragma unroll
      for (int q = 0; q < 4; ++q) acc[q] = (f32x4){0.f, 0.f, 0.f, 0.f};
      if (t >= 1) {
        #pragma unroll
        for (int i = 0; i < 4; ++i) {
          const f16x8 A = *(const f16x8*)(ldsH + rpar * 8192 + (lk + i) * 1024 + lane * 16);
          #pragma unroll
          for (int q = 0; q < 4; ++q)
            acc[q] = __builtin_amdgcn_mfma_f32_16x16x32_f16(A, W[q][lk + i], acc[q], 0, 0, 0);
        }
      }
      // ---- phase B: wait + combined tag check (cooperative) ----
      const unsigned patX = (((unsigned)t >> 2) & 1u) * 0x00010001u;
      const unsigned patA = (((unsigned)(t - 1) >> 1) & 1u) * 0x00010001u;
      wvm0();
      for (;;) {
        u32x4 d = ((x0 ^ patX) | (x1 ^ patX)) & 0x00010001u;
        unsigned bad = d[0] | d[1] | d[2] | d[3];
        if (hasA) { const u32x4 e = (va ^ patA) & 0x00010001u;
                    bad |= e[0] | e[1] | e[2] | e[3]; }
        if (__all(bad == 0)) break;
        x0 = ld16(sx + tid * 32); x1 = ld16(sx + tid * 32 + 16);
        if (hasA) va = ld16(pa);
        wvm0();
      }
      *(u32x4*)(ldsX + (t & 1) * 16384 + tid * 32)      = x0;
      *(u32x4*)(ldsX + (t & 1) * 16384 + tid * 32 + 16) = x1;
      if (hasA) *(u32x4*)(ldsH + rpar * 8192 + pb + tid * 16) = va;
      barrier_lds();
      if (tid == 0) stp(prog + 2 + half, (unsigned)(t + 1));
      // ---- phase C: partner MFMAs + xg add + elementwise + stores ----
      if (t >= 1) {
        #pragma unroll
        for (int i = 0; i < 4; ++i) {
          const f16x8 A = *(const f16x8*)(ldsH + rpar * 8192 + (pk + i) * 1024 + lane * 16);
          #pragma unroll
          for (int q = 0; q < 4; ++q)
            acc[q] = __builtin_amdgcn_mfma_f32_16x16x32_f16(A, W[q][pk + i], acc[q], 0, 0, 0);
        }
      }
      const char* xl = ldsX + (t & 1) * 16384;
      #pragma unroll
      for (int q = 0; q < 4; ++q)
        #pragma unroll
        for (int r = 0; r < 4; ++r) {
          const unsigned short xv = *(const unsigned short*)
            (xl + (brow + r) * 1024 + (q * 128 + wv * 16 + col16) * 2);
          acc[q][r] += (float)__builtin_bit_cast(_Float16, xv);
        }
      char* d1 = h1r + (size_t)(t & 1) * 8192;
      const unsigned wt = ((unsigned)t >> 1) & 1u;
      #pragma unroll
      for (int r = 0; r < 4; ++r) {
        const float iv = sigm(acc[0][r]), fv = sigm(acc[1][r]);
        const float gv = tanh_(acc[2][r]), ov = sigm(acc[3][r]);
        cst[r] = fv * cst[r] + iv * gv;
        const float h = ov * tanh_(cst[r]);
        if (t < TT - 1) {
          unsigned short hb = __builtin_bit_cast(unsigned short, (_Float16)h);
          hb = (unsigned short)((hb & 0xFFFEu) | wt);
          const unsigned fo = ubase + ((unsigned)(brow + r) << 4);
          st2(d1 + fo, (unsigned)hb);
          *(unsigned short*)(ldsH + (t & 1) * 8192 + fo) = hb;
        } else {
          out[(size_t)(g * 16 + brow + r) * HH + unit] = h;
        }
      }
    }
  }
}

// ================= fallback: round-9 kernel (1580us proven) =================
__global__ void fb_init(uint4* p, int n) {
  int i = blockIdx.x * blockDim.x + threadIdx.x;
  if (i < n) p[i] = make_uint4(0x00010001u,0x00010001u,0x00010001u,0x00010001u);
}
__device__ __forceinline__ unsigned fb_tg(int t){ return ((unsigned)(t + 4) >> 1) & 1u; }

__global__ __launch_bounds__(512) void lstm_v9(
    const float* __restrict__ M,
    const float* __restrict__ Wih0, const float* __restrict__ Whh0,
    const float* __restrict__ bih0, const float* __restrict__ bhh0,
    const float* __restrict__ Wih1, const float* __restrict__ Whh1,
    const float* __restrict__ bih1, const float* __restrict__ bhh1,
    float* __restrict__ out, char* __restrict__ ws)
{
  __shared__ __align__(16) char  ldsA[16384];
  __shared__ __align__(16) f32x4 xch[8][64];
  const int tid  = threadIdx.x, lane = tid & 63, wv = tid >> 6;
  const int g = blockIdx.x & 7, w = blockIdx.x >> 3;
  const int hf = wv & 1, role = wv >> 1;
  const int col16 = lane & 15, ko8 = (lane >> 4) << 3;
  const int unit = w * 16 + col16;
  #define H0R(slot) (ws + (((g << 1) | (slot)) << 14))
  #define H1R(slot) (ws + 262144 + (((g << 1) | (slot)) << 14))
  f16x8 W0[4][8], WI[4];
  float bias[4] = {0.f, 0.f, 0.f, 0.f};
  if (role == 0) {
    #pragma unroll
    for (int q = 0; q < 4; ++q) {
      const int row = q * HH + unit;
      #pragma unroll
      for (int kt = 0; kt < 8; ++kt) W0[q][kt] = cvt8(Whh0 + (size_t)row*HH + kt*32 + ko8);
      WI[q] = cvt8(Wih0 + (size_t)row*32 + ko8); bias[q] = bih0[row] + bhh0[row];
    }
  } else if (role == 1) {
    #pragma unroll
    for (int q = 0; q < 4; ++q) {
      const int row = q * HH + unit;
      #pragma unroll
      for (int kt = 0; kt < 8; ++kt) W0[q][kt] = cvt8(Wih1 + (size_t)row*HH + kt*32 + ko8);
      bias[q] = bih1[row] + bhh1[row];
    }
  } else if (role == 2) {
    #pragma unroll
    for (int q = 0; q < 4; ++q) {
      const int row = q * HH + unit;
      #pragma unroll
      for (int kt = 0; kt < 8; ++kt) W0[q][kt] = cvt8(Whh1 + (size_t)row*HH + kt*32 + ko8);
    }
  }
  const int sl = tid & 63, skt = (tid >> 6) & 7;
  const unsigned moff0 = (unsigned)((sl & 15) * 512 + skt * 64 + (sl >> 4) * 16);
  const unsigned moff1 = moff0 + 16 * 512;
  const unsigned lo    = (unsigned)(skt * 1024 + sl * 16);
  const unsigned hoff = (((unsigned)(hf*16 + col16)) << 9) | ((unsigned)(lane >> 4) << 4);
  unsigned soff[4];
  #pragma unroll
  for (int r = 0; r < 4; ++r)
    soff[r] = (((unsigned)(hf*16 + ((lane>>4)<<2) + r)) << 9) | ((unsigned)unit << 1);
  const float* mp = M + (size_t)(g*32 + hf*16 + col16) * TT * 32 + ko8;
  float4 m0 = {0,0,0,0}, m1 = {0,0,0,0};
  if (role == 0) { m0 = *(const float4*)mp; m1 = *(const float4*)(mp + 4); }
  float cst[4] = {0.f, 0.f, 0.f, 0.f};
  for (int p = 0; p <= TT; ++p) {
    if (p >= 1) {
      const char* s = H0R((p - 1) & 1);
      const unsigned pat = fb_tg(p - 1) * 0x00010001u;
      u32x4 v0 = ld16(s + moff0), v1 = ld16(s + moff1);
      wvm0();
      for (;;) {
        const u32x4 d = ((v0 ^ pat) | (v1 ^ pat)) & 0x00010001u;
        if (__all((d[0] | d[1] | d[2] | d[3]) == 0)) break;
        v0 = ld16(s + moff0); v1 = ld16(s + moff1); wvm0();
      }
      *(u32x4*)(ldsA + lo) = v0; *(u32x4*)(ldsA + 8192 + lo) = v1;
    }
    barrier_lds();
    f32x4 acc[4];
    if (role == 0 && p < TT) {
      f16x8 am;
      am[0]=(_Float16)m0.x; am[1]=(_Float16)m0.y; am[2]=(_Float16)m0.z; am[3]=(_Float16)m0.w;
      am[4]=(_Float16)m1.x; am[5]=(_Float16)m1.y; am[6]=(_Float16)m1.z; am[7]=(_Float16)m1.w;
      #pragma unroll
      for (int q = 0; q < 4; ++q) {
        acc[q] = (f32x4){bias[q], bias[q], bias[q], bias[q]};
        acc[q] = __builtin_amdgcn_mfma_f32_16x16x32_f16(am, WI[q], acc[q], 0, 0, 0);
      }
      if (p >= 1) {
        #pragma unroll
        for (int kt = 0; kt < 8; ++kt) {
          const f16x8 A = *(const f16x8*)(ldsA + hf*8192 + kt*1024 + lane*16);
          #pragma unroll
          for (int q = 0; q < 4; ++q)
            acc[q] = __builtin_amdgcn_mfma_f32_16x16x32_f16(A, W0[q][kt], acc[q], 0, 0, 0);
        }
      }
      char* d = H0R(p & 1);
      const unsigned wt = fb_tg(p);
      #pragma unroll
      for (int r = 0; r < 4; ++r) {
        const float iv = sigm(acc[0][r]), fv = sigm(acc[1][r]);
        const float gv = tanh_(acc[2][r]), ov = sigm(acc[3][r]);
        cst[r] = fv * cst[r] + iv * gv;
        const float h = ov * tanh_(cst[r]);
        unsigned short hb = __builtin_bit_cast(unsigned short, (_Float16)h);
        hb = (unsigned short)((hb & 0xFFFEu) | wt);
        st2(d + soff[r], (unsigned)hb);
      }
      if (p + 1 < TT) { m0 = *(const float4*)(mp + (p+1)*32); m1 = *(const float4*)(mp + (p+1)*32 + 4); }
    } else if (role == 1 && p >= 1) {
      #pragma unroll
      for (int q = 0; q < 4; ++q) acc[q] = (f32x4){bias[q], bias[q], bias[q], bias[q]};
      #pragma unroll
      for (int kt = 0; kt < 8; ++kt) {
        const f16x8 A = *(const f16x8*)(ldsA + hf*8192 + kt*1024 + lane*16);
        #pragma unroll
        for (int q = 0; q < 4; ++q)
          acc[q] = __builtin_amdgcn_mfma_f32_16x16x32_f16(A, W0[q][kt], acc[q], 0, 0, 0);
      }
    } else if (role == 2 && p >= 2) {
      const char* s = H1R(p & 1);
      const unsigned pat = fb_tg(p - 2) * 0x00010001u;
      u32x4 hb[8];
      #pragma unroll
      for (int k = 0; k < 8; ++k) hb[k] = ld16(s + hoff + k*64);
      wvm0();
      for (;;) {
        unsigned bad = 0;
        #pragma unroll
        for (int k = 0; k < 8; ++k) {
          const u32x4 d = (hb[k] ^ pat) & 0x00010001u;
          bad |= d[0] | d[1] | d[2] | d[3];
        }
        if (__all(bad == 0)) break;
        #pragma unroll
        for (int k = 0; k < 8; ++k) hb[k] = ld16(s + hoff + k*64);
        wvm0();
      }
      #pragma unroll
      for (int q = 0; q < 4; ++q) acc[q] = (f32x4){0.f, 0.f, 0.f, 0.f};
      #pragma unroll
      for (int kt = 0; kt < 8; ++kt) {
        const f16x8 A = __builtin_bit_cast(f16x8, hb[kt]);
        #pragma unroll
        for (int q = 0; q < 4; ++q)
          acc[q] = __builtin_amdgcn_mfma_f32_16x16x32_f16(A, W0[q][kt], acc[q], 0, 0, 0);
      }
      #pragma unroll
      for (int q = 0; q < 4; ++q) xch[hf*4 + q][lane] = acc[q];
    }
    barrier_lds();
    if (role == 1 && p >= 1) {
      if (p >= 2) {
        #pragma unroll
        for (int q = 0; q < 4; ++q) acc[q] = acc[q] + xch[hf*4 + q][lane];
      }
      if (p < TT) {
        char* d = H1R((p - 1) & 1);
        const unsigned wt = fb_tg(p - 1);
        #pragma unroll
        for (int r = 0; r < 4; ++r) {
          const float iv = sigm(acc[0][r]), fv = sigm(acc[1][r]);
          const float gv = tanh_(acc[2][r]), ov = sigm(acc[3][r]);
          cst[r] = fv * cst[r] + iv * gv;
          const float h = ov * tanh_(cst[r]);
          unsigned short hb = __builtin_bit_cast(unsigned short, (_Float16)h);
          hb = (unsigned short)((hb & 0xFFFEu) | wt);
          st2(d + soff[r], (unsigned)hb);
        }
      } else {
        #pragma unroll
        for (int r = 0; r < 4; ++r) {
          const float iv = sigm(acc[0][r]), fv = sigm(acc[1][r]);
          const float gv = tanh_(acc[2][r]), ov = sigm(acc[3][r]);
          cst[r] = fv * cst[r] + iv * gv;
          const float h = ov * tanh_(cst[r]);
          const int b = hf*16 + ((lane>>4)<<2) + r;
          out[(size_t)(g*32 + b) * HH + (w*16 + col16)] = h;
        }
      }
    }
  }
  #undef H0R
  #undef H1R
}

extern "C" void kernel_launch(void* const* d_in, const int* in_sizes, int n_in,
                              void* d_out, int out_size, void* d_ws, size_t ws_size,
                              hipStream_t stream) {
  (void)in_sizes; (void)n_in; (void)out_size;
  const float* M    = (const float*)d_in[0];
  const float* Wih0 = (const float*)d_in[1];
  const float* Whh0 = (const float*)d_in[2];
  const float* bih0 = (const float*)d_in[3];
  const float* bhh0 = (const float*)d_in[4];
  const float* Wih1 = (const float*)d_in[5];
  const float* Whh1 = (const float*)d_in[6];
  const float* bih1 = (const float*)d_in[7];
  const float* bhh1 = (const float*)d_in[8];

  if (ws_size >= (size_t)16 * GS) {
    const int n16 = 16 * (GS / 16);
    init_ws<<<(n16 + 255) / 256, 256, 0, stream>>>((uint4*)d_ws, n16);
    lstm_v15<<<96, 512, 0, stream>>>(M, Wih0, Whh0, bih0, bhh0,
                                     Wih1, Whh1, bih1, bhh1,
                                     (float*)d_out, (char*)d_ws);
  } else {
    if (ws_size < 524288) return;
    fb_init<<<128, 256, 0, stream>>>((uint4*)d_ws, 32768);
    lstm_v9<<<128, 512, 0, stream>>>(M, Wih0, Whh0, bih0, bhh0,
                                     Wih1, Whh1, bih1, bhh1,
                                     (float*)d_out, (char*)d_ws);
  }
}

// Round 16
// 1198.506 us; speedup vs baseline: 4.0569x; 3.8652x over previous
//
#include <hip/hip_runtime.h>
#include <hip/hip_fp16.h>

// 2-layer LSTM B=256 T=512 I=32 H=256.  r12 protocol, re-geometried so weights
// are TRULY register-resident: 256-thr wgs (4 waves) + __launch_bounds__(256,1)
// => VGPR cap 512 (r3 evidence: (128,1) gave 216; 512-thr wgs pin at 128 and
// spill the weights to scratch -- the hidden per-step cost since r9).
// 16 groups x 16 batches x 12 wgs: L0 x4 quarters (64 units, Whh0+Wih0 regs),
// W1 x4 (Wih1, h0->xg quarter streams), L1 x4 (Whh1 + xg add + output).
// Transport (all sc0 sc1 MALL, fp16-LSB lap tags, fire-and-forget stores):
//   h0 ring 16 slots x 8KB (writers L0, readers L0+W1; throttle min W1prog)
//   xg ring  4 slots x 4 x 8KB (W1q -> L1q; throttle L1prog)
//   h1 ring  2 slots x 8KB (L1 quarters, skew<=1 structural)
// Cooperative staging only (2x16B/thread/buffer), 2-parity LDS, 1 barrier/step.
// Fallback: r9 kernel (1580us proven) when ws too small.

#define TT 512
#define HH 256
#define GS 294912   // per-group: 128K h0 + 16K h1r + 128K xg + prog

typedef _Float16 f16x8 __attribute__((ext_vector_type(8)));
typedef float    f32x4 __attribute__((ext_vector_type(4)));
typedef unsigned u32x4 __attribute__((ext_vector_type(4)));

__device__ __forceinline__ f16x8 cvt8(const float* p) {
  const float4 a = *(const float4*)p;
  const float4 b = *(const float4*)(p + 4);
  f16x8 r;
  r[0]=(_Float16)a.x; r[1]=(_Float16)a.y; r[2]=(_Float16)a.z; r[3]=(_Float16)a.w;
  r[4]=(_Float16)b.x; r[5]=(_Float16)b.y; r[6]=(_Float16)b.z; r[7]=(_Float16)b.w;
  return r;
}
__device__ __forceinline__ float sigm(float x){ return 1.f/(1.f + __expf(-x)); }
__device__ __forceinline__ float tanh_(float x){ return 1.f - 2.f/(1.f + __expf(2.f*x)); }

// ---- MALL-coherent (L2-bypass) primitives, per-lane 64b addressing ----
__device__ __forceinline__ u32x4 ld16(const void* p) {
  u32x4 r;
  asm volatile("global_load_dwordx4 %0, %1, off sc0 sc1"
               : "=v"(r) : "v"(p) : "memory");
  return r;
}
__device__ __forceinline__ void st2(void* p, unsigned v) {
  asm volatile("global_store_short %0, %1, off sc0 sc1"
               :: "v"(p), "v"(v) : "memory");
}
__device__ __forceinline__ void stp(void* p, unsigned v) {
  asm volatile("global_store_dword %0, %1, off sc0 sc1"
               :: "v"(p), "v"(v) : "memory");
}
__device__ __forceinline__ unsigned ldp(const void* p) {
  unsigned r;
  asm volatile("global_load_dword %0, %1, off sc0 sc1\n\ts_waitcnt vmcnt(0)"
               : "=v"(r) : "v"(p) : "memory");
  return r;
}
__device__ __forceinline__ u32x4 ldp4(const void* p) {
  u32x4 r;
  asm volatile("global_load_dwordx4 %0, %1, off sc0 sc1\n\ts_waitcnt vmcnt(0)"
               : "=v"(r) : "v"(p) : "memory");
  return r;
}
__device__ __forceinline__ void wvm0() {
  asm volatile("s_waitcnt vmcnt(0)" ::: "memory");
  __builtin_amdgcn_sched_barrier(0);
}
__device__ __forceinline__ void barrier_lds() {
  __builtin_amdgcn_sched_barrier(0);
  asm volatile("s_waitcnt lgkmcnt(0)" ::: "memory");
  __builtin_amdgcn_s_barrier();
  __builtin_amdgcn_sched_barrier(0);
}

__global__ void init_ws(uint4* p, int n) {
  int i = blockIdx.x * blockDim.x + threadIdx.x;
  if (i >= n) return;
  int rem = i % (GS / 16);
  p[i] = (rem < 17408) ? make_uint4(0x00010001u,0x00010001u,0x00010001u,0x00010001u)
                       : make_uint4(0u,0u,0u,0u);   // prog dwords = 0
}

__global__ __launch_bounds__(256, 1) void lstm_v16(
    const float* __restrict__ M,
    const float* __restrict__ Wih0, const float* __restrict__ Whh0,
    const float* __restrict__ bih0, const float* __restrict__ bhh0,
    const float* __restrict__ Wih1, const float* __restrict__ Whh1,
    const float* __restrict__ bih1, const float* __restrict__ bhh1,
    float* __restrict__ out, char* __restrict__ ws)
{
  __shared__ __align__(16) char ldsA[16384];   // 2-parity staged A-frag buffer
  __shared__ __align__(16) char ldsB[16384];   // L1 only: 2-parity staged xg

  const int tid  = threadIdx.x, lane = tid & 63, wv = tid >> 6;   // 4 waves
  const int bid  = blockIdx.x;
  const int g    = bid / 12;
  const int idx  = bid - g * 12;
  const int role = idx >> 2;           // 0:L0 1:W1 2:L1
  const int q4   = idx & 3;            // quarter
  const int col16 = lane & 15, ko8 = (lane >> 4) << 3, brow = (lane >> 4) << 2;
  const int unit = q4 * 64 + wv * 16 + col16;    // 0..255

  char* base   = ws + (size_t)g * GS;
  char* stream = base;                 // h0: 16 slots x 8KB, A-frag layout
  char* h1r    = base + 131072;        // h1: 2 slots x 8KB, A-frag layout
  char* xg     = base + 147456;        // xg: 4 slots x [4 quarter x 8KB]
  int*  prog   = (int*)(base + 278528);   // [0..3]=W1 quarters [4..7]=L1 quarters

  // A-frag byte position of (batch b, unit u): ubase|(b<<4)  [r10-validated]
  const unsigned ubase = ((unsigned)(unit >> 5) << 10)
                       | ((unsigned)((unit >> 3) & 3) << 8)
                       | ((unsigned)(unit & 7) << 1);

  // ---- register-resident weights: 4 gates x 16 units x K=256 (this wave) ----
  f16x8 W[4][8], WI[4];
  float bias[4] = {0.f, 0.f, 0.f, 0.f};
  {
    const float* Wsrc = (role == 0) ? Whh0 : (role == 1) ? Wih1 : Whh1;
    #pragma unroll
    for (int q = 0; q < 4; ++q) {
      const int row = q * HH + unit;
      #pragma unroll
      for (int kt = 0; kt < 8; ++kt)
        W[q][kt] = cvt8(Wsrc + (size_t)row * HH + kt * 32 + ko8);
      if (role == 0) { WI[q] = cvt8(Wih0 + (size_t)row * 32 + ko8);
                       bias[q] = bih0[row] + bhh0[row]; }
      else if (role == 1) bias[q] = bih1[row] + bhh1[row];
    }
  }

  float cst[4] = {0.f, 0.f, 0.f, 0.f};

  if (role == 0) {
    // ============ L0 quarters: latency-critical recurrence ============
    const float* mp = M + (size_t)(g * 16 + col16) * TT * 32 + ko8;
    float4 m0 = *(const float4*)mp, m1 = *(const float4*)(mp + 4);
    int lastW = 0;
    for (int t = 0; t < TT; ++t) {
      const int par = t & 1;
      if (t >= 1) {                    // cooperative stage h0[t-1] (8KB)
        const char* s = stream + (size_t)((t - 1) & 15) * 8192 + tid * 16;
        const unsigned pat = (((unsigned)(t - 1) >> 4) & 1u) * 0x00010001u;
        u32x4 v0 = ld16(s), v1 = ld16(s + 4096);
        wvm0();
        for (;;) {
          const u32x4 d = ((v0 ^ pat) | (v1 ^ pat)) & 0x00010001u;
          if (__all((d[0] | d[1] | d[2] | d[3]) == 0)) break;
          v0 = ld16(s); v1 = ld16(s + 4096);
          wvm0();
        }
        *(u32x4*)(ldsA + par * 8192 + tid * 16)        = v0;
        *(u32x4*)(ldsA + par * 8192 + tid * 16 + 4096) = v1;
      }
      barrier_lds();
      f32x4 acc[4];
      f16x8 am;
      am[0]=(_Float16)m0.x; am[1]=(_Float16)m0.y; am[2]=(_Float16)m0.z; am[3]=(_Float16)m0.w;
      am[4]=(_Float16)m1.x; am[5]=(_Float16)m1.y; am[6]=(_Float16)m1.z; am[7]=(_Float16)m1.w;
      #pragma unroll
      for (int q = 0; q < 4; ++q) {
        acc[q] = (f32x4){bias[q], bias[q], bias[q], bias[q]};
        acc[q] = __builtin_amdgcn_mfma_f32_16x16x32_f16(am, WI[q], acc[q], 0, 0, 0);
      }
      if (t >= 1) {
        #pragma unroll
        for (int kt = 0; kt < 8; ++kt) {
          const f16x8 A = *(const f16x8*)(ldsA + par * 8192 + kt * 1024 + lane * 16);
          #pragma unroll
          for (int q = 0; q < 4; ++q)
            acc[q] = __builtin_amdgcn_mfma_f32_16x16x32_f16(A, W[q][kt], acc[q], 0, 0, 0);
        }
      }
      if (t + 1 < TT) { m0 = *(const float4*)(mp + (t + 1) * 32);
                        m1 = *(const float4*)(mp + (t + 1) * 32 + 4); }
      if (t >= 16) {                   // slot overwrite throttle vs W1 quarters
        while (lastW < t - 15) {
          const u32x4 d = ldp4(prog);
          int m = (int)d[0];
          m = m < (int)d[1] ? m : (int)d[1];
          m = m < (int)d[2] ? m : (int)d[2];
          m = m < (int)d[3] ? m : (int)d[3];
          lastW = m;
        }
      }
      char* slot = stream + (size_t)(t & 15) * 8192;
      const unsigned wt = ((unsigned)t >> 4) & 1u;
      #pragma unroll
      for (int r = 0; r < 4; ++r) {
        const float iv = sigm(acc[0][r]), fv = sigm(acc[1][r]);
        const float gv = tanh_(acc[2][r]), ov = sigm(acc[3][r]);
        cst[r] = fv * cst[r] + iv * gv;
        const float h = ov * tanh_(cst[r]);
        unsigned short hb = __builtin_bit_cast(unsigned short, (_Float16)h);
        hb = (unsigned short)((hb & 0xFFFEu) | wt);
        st2(slot + ubase + ((unsigned)(brow + r) << 4), (unsigned)hb);
      }
    }
  } else if (role == 1) {
    // ============ W1 quarters: Wih1*h0 -> per-quarter xg stream ============
    int lastL = 0;
    for (int t = 0; t < TT; ++t) {
      const int par = t & 1;
      {                                // cooperative stage h0[t] (8KB)
        const char* s = stream + (size_t)(t & 15) * 8192 + tid * 16;
        const unsigned pat = (((unsigned)t >> 4) & 1u) * 0x00010001u;
        u32x4 v0 = ld16(s), v1 = ld16(s + 4096);
        wvm0();
        for (;;) {
          const u32x4 d = ((v0 ^ pat) | (v1 ^ pat)) & 0x00010001u;
          if (__all((d[0] | d[1] | d[2] | d[3]) == 0)) break;
          v0 = ld16(s); v1 = ld16(s + 4096);
          wvm0();
        }
        *(u32x4*)(ldsA + par * 8192 + tid * 16)        = v0;
        *(u32x4*)(ldsA + par * 8192 + tid * 16 + 4096) = v1;
      }
      barrier_lds();
      if (tid == 0) stp(prog + q4, (unsigned)(t + 1));
      if (t >= 4) { while (lastL < t - 3) lastL = (int)ldp(prog + 4 + q4); }
      f32x4 acc[4];
      #pragma unroll
      for (int q = 0; q < 4; ++q)
        acc[q] = (f32x4){bias[q], bias[q], bias[q], bias[q]};
      #pragma unroll
      for (int kt = 0; kt < 8; ++kt) {
        const f16x8 A = *(const f16x8*)(ldsA + par * 8192 + kt * 1024 + lane * 16);
        #pragma unroll
        for (int q = 0; q < 4; ++q)
          acc[q] = __builtin_amdgcn_mfma_f32_16x16x32_f16(A, W[q][kt], acc[q], 0, 0, 0);
      }
      // store xg quarter-region: [16b][4 gates x 64 units] fp16, tagged
      char* xs = xg + (size_t)(t & 3) * 32768 + q4 * 8192;
      const unsigned wtx = ((unsigned)t >> 2) & 1u;
      #pragma unroll
      for (int q = 0; q < 4; ++q)
        #pragma unroll
        for (int r = 0; r < 4; ++r) {
          unsigned short hb = __builtin_bit_cast(unsigned short, (_Float16)acc[q][r]);
          hb = (unsigned short)((hb & 0xFFFEu) | wtx);
          const unsigned off = (unsigned)(brow + r) * 512
                             + (unsigned)(q * 64 + wv * 16 + col16) * 2;
          st2(xs + off, (unsigned)hb);
        }
    }
  } else {
    // ============ L1 quarters: recurrence + xg add + output ============
    for (int t = 0; t < TT; ++t) {
      const int par = t & 1;
      {                                // stage xg[t] quarter (8KB) + h1[t-1] (8KB)
        const char* sx = xg + (size_t)(t & 3) * 32768 + q4 * 8192 + tid * 16;
        const unsigned patX = (((unsigned)t >> 2) & 1u) * 0x00010001u;
        const char* sh = h1r + (size_t)((t - 1) & 1) * 8192 + tid * 16;
        const unsigned patH = (((unsigned)(t - 1) >> 1) & 1u) * 0x00010001u;
        const bool hasH = (t >= 1);
        u32x4 x0 = ld16(sx), x1 = ld16(sx + 4096), h0v, h1v;
        if (hasH) { h0v = ld16(sh); h1v = ld16(sh + 4096); }
        wvm0();
        for (;;) {
          u32x4 d = ((x0 ^ patX) | (x1 ^ patX)) & 0x00010001u;
          unsigned bad = d[0] | d[1] | d[2] | d[3];
          if (hasH) {
            const u32x4 e = ((h0v ^ patH) | (h1v ^ patH)) & 0x00010001u;
            bad |= e[0] | e[1] | e[2] | e[3];
          }
          if (__all(bad == 0)) break;
          x0 = ld16(sx); x1 = ld16(sx + 4096);
          if (hasH) { h0v = ld16(sh); h1v = ld16(sh + 4096); }
          wvm0();
        }
        *(u32x4*)(ldsB + par * 8192 + tid * 16)        = x0;
        *(u32x4*)(ldsB + par * 8192 + tid * 16 + 4096) = x1;
        if (hasH) {
          *(u32x4*)(ldsA + par * 8192 + tid * 16)        = h0v;
          *(u32x4*)(ldsA + par * 8192 + tid * 16 + 4096) = h1v;
        }
      }
      barrier_lds();
      if (tid == 0) stp(prog + 4 + q4, (unsigned)(t + 1));
      f32x4 acc[4];
      #pragma unroll
      for (int q = 0; q < 4; ++q) acc[q] = (f32x4){0.f, 0.f, 0.f, 0.f};
      if (t >= 1) {
        #pragma unroll
        for (int kt = 0; kt < 8; ++kt) {
          const f16x8 A = *(const f16x8*)(ldsA + par * 8192 + kt * 1024 + lane * 16);
          #pragma unroll
          for (int q = 0; q < 4; ++q)
            acc[q] = __builtin_amdgcn_mfma_f32_16x16x32_f16(A, W[q][kt], acc[q], 0, 0, 0);
        }
      }
      const char* xl = ldsB + par * 8192;
      #pragma unroll
      for (int q = 0; q < 4; ++q)
        #pragma unroll
        for (int r = 0; r < 4; ++r) {
          const unsigned short xv = *(const unsigned short*)
            (xl + (brow + r) * 512 + (q * 64 + wv * 16 + col16) * 2);
          acc[q][r] += (float)__builtin_bit_cast(_Float16, xv);
        }
      char* d1 = h1r + (size_t)par * 8192;
      const unsigned wt = ((unsigned)t >> 1) & 1u;
      #pragma unroll
      for (int r = 0; r < 4; ++r) {
        const float iv = sigm(acc[0][r]), fv = sigm(acc[1][r]);
        const float gv = tanh_(acc[2][r]), ov = sigm(acc[3][r]);
        cst[r] = fv * cst[r] + iv * gv;
        const float h = ov * tanh_(cst[r]);
        if (t < TT - 1) {
          unsigned short hb = __builtin_bit_cast(unsigned short, (_Float16)h);
          hb = (unsigned short)((hb & 0xFFFEu) | wt);
          st2(d1 + ubase + ((unsigned)(brow + r) << 4), (unsigned)hb);
        } else {
          out[(size_t)(g * 16 + brow + r) * HH + unit] = h;   // final h1, fp32
        }
      }
    }
  }
}

// ================= fallback: round-9 kernel (1580us proven) =================
__global__ void fb_init(uint4* p, int n) {
  int i = blockIdx.x * blockDim.x + threadIdx.x;
  if (i < n) p[i] = make_uint4(0x00010001u,0x00010001u,0x00010001u,0x00010001u);
}
__device__ __forceinline__ unsigned fb_tg(int t){ return ((unsigned)(t + 4) >> 1) & 1u; }

__global__ __launch_bounds__(512) void lstm_v9(
    const float* __restrict__ M,
    const float* __restrict__ Wih0, const float* __restrict__ Whh0,
    const float* __restrict__ bih0, const float* __restrict__ bhh0,
    const float* __restrict__ Wih1, const float* __restrict__ Whh1,
    const float* __restrict__ bih1, const float* __restrict__ bhh1,
    float* __restrict__ out, char* __restrict__ ws)
{
  __shared__ __align__(16) char  ldsA[16384];
  __shared__ __align__(16) f32x4 xch[8][64];
  const int tid  = threadIdx.x, lane = tid & 63, wv = tid >> 6;
  const int g = blockIdx.x & 7, w = blockIdx.x >> 3;
  const int hf = wv & 1, role = wv >> 1;
  const int col16 = lane & 15, ko8 = (lane >> 4) << 3;
  const int unit = w * 16 + col16;
  #define H0R(slot) (ws + (((g << 1) | (slot)) << 14))
  #define H1R(slot) (ws + 262144 + (((g << 1) | (slot)) << 14))
  f16x8 W0[4][8], WI[4];
  float bias[4] = {0.f, 0.f, 0.f, 0.f};
  if (role == 0) {
    #pragma unroll
    for (int q = 0; q < 4; ++q) {
      const int row = q * HH + unit;
      #pragma unroll
      for (int kt = 0; kt < 8; ++kt) W0[q][kt] = cvt8(Whh0 + (size_t)row*HH + kt*32 + ko8);
      WI[q] = cvt8(Wih0 + (size_t)row*32 + ko8); bias[q] = bih0[row] + bhh0[row];
    }
  } else if (role == 1) {
    #pragma unroll
    for (int q = 0; q < 4; ++q) {
      const int row = q * HH + unit;
      #pragma unroll
      for (int kt = 0; kt < 8; ++kt) W0[q][kt] = cvt8(Wih1 + (size_t)row*HH + kt*32 + ko8);
      bias[q] = bih1[row] + bhh1[row];
    }
  } else if (role == 2) {
    #pragma unroll
    for (int q = 0; q < 4; ++q) {
      const int row = q * HH + unit;
      #pragma unroll
      for (int kt = 0; kt < 8; ++kt) W0[q][kt] = cvt8(Whh1 + (size_t)row*HH + kt*32 + ko8);
    }
  }
  const int sl = tid & 63, skt = (tid >> 6) & 7;
  const unsigned moff0 = (unsigned)((sl & 15) * 512 + skt * 64 + (sl >> 4) * 16);
  const unsigned moff1 = moff0 + 16 * 512;
  const unsigned lo    = (unsigned)(skt * 1024 + sl * 16);
  const unsigned hoff = (((unsigned)(hf*16 + col16)) << 9) | ((unsigned)(lane >> 4) << 4);
  unsigned soff[4];
  #pragma unroll
  for (int r = 0; r < 4; ++r)
    soff[r] = (((unsigned)(hf*16 + ((lane>>4)<<2) + r)) << 9) | ((unsigned)unit << 1);
  const float* mp = M + (size_t)(g*32 + hf*16 + col16) * TT * 32 + ko8;
  float4 m0 = {0,0,0,0}, m1 = {0,0,0,0};
  if (role == 0) { m0 = *(const float4*)mp; m1 = *(const float4*)(mp + 4); }
  float cst[4] = {0.f, 0.f, 0.f, 0.f};
  for (int p = 0; p <= TT; ++p) {
    if (p >= 1) {
      const char* s = H0R((p - 1) & 1);
      const unsigned pat = fb_tg(p - 1) * 0x00010001u;
      u32x4 v0 = ld16(s + moff0), v1 = ld16(s + moff1);
      wvm0();
      for (;;) {
        const u32x4 d = ((v0 ^ pat) | (v1 ^ pat)) & 0x00010001u;
        if (__all((d[0] | d[1] | d[2] | d[3]) == 0)) break;
        v0 = ld16(s + moff0); v1 = ld16(s + moff1); wvm0();
      }
      *(u32x4*)(ldsA + lo) = v0; *(u32x4*)(ldsA + 8192 + lo) = v1;
    }
    barrier_lds();
    f32x4 acc[4];
    if (role == 0 && p < TT) {
      f16x8 am;
      am[0]=(_Float16)m0.x; am[1]=(_Float16)m0.y; am[2]=(_Float16)m0.z; am[3]=(_Float16)m0.w;
      am[4]=(_Float16)m1.x; am[5]=(_Float16)m1.y; am[6]=(_Float16)m1.z; am[7]=(_Float16)m1.w;
      #pragma unroll
      for (int q = 0; q < 4; ++q) {
        acc[q] = (f32x4){bias[q], bias[q], bias[q], bias[q]};
        acc[q] = __builtin_amdgcn_mfma_f32_16x16x32_f16(am, WI[q], acc[q], 0, 0, 0);
      }
      if (p >= 1) {
        #pragma unroll
        for (int kt = 0; kt < 8; ++kt) {
          const f16x8 A = *(const f16x8*)(ldsA + hf*8192 + kt*1024 + lane*16);
          #pragma unroll
          for (int q = 0; q < 4; ++q)
            acc[q] = __builtin_amdgcn_mfma_f32_16x16x32_f16(A, W0[q][kt], acc[q], 0, 0, 0);
        }
      }
      char* d = H0R(p & 1);
      const unsigned wt = fb_tg(p);
      #pragma unroll
      for (int r = 0; r < 4; ++r) {
        const float iv = sigm(acc[0][r]), fv = sigm(acc[1][r]);
        const float gv = tanh_(acc[2][r]), ov = sigm(acc[3][r]);
        cst[r] = fv * cst[r] + iv * gv;
        const float h = ov * tanh_(cst[r]);
        unsigned short hb = __builtin_bit_cast(unsigned short, (_Float16)h);
        hb = (unsigned short)((hb & 0xFFFEu) | wt);
        st2(d + soff[r], (unsigned)hb);
      }
      if (p + 1 < TT) { m0 = *(const float4*)(mp + (p+1)*32); m1 = *(const float4*)(mp + (p+1)*32 + 4); }
    } else if (role == 1 && p >= 1) {
      #pragma unroll
      for (int q = 0; q < 4; ++q) acc[q] = (f32x4){bias[q], bias[q], bias[q], bias[q]};
      #pragma unroll
      for (int kt = 0; kt < 8; ++kt) {
        const f16x8 A = *(const f16x8*)(ldsA + hf*8192 + kt*1024 + lane*16);
        #pragma unroll
        for (int q = 0; q < 4; ++q)
          acc[q] = __builtin_amdgcn_mfma_f32_16x16x32_f16(A, W0[q][kt], acc[q], 0, 0, 0);
      }
    } else if (role == 2 && p >= 2) {
      const char* s = H1R(p & 1);
      const unsigned pat = fb_tg(p - 2) * 0x00010001u;
      u32x4 hb[8];
      #pragma unroll
      for (int k = 0; k < 8; ++k) hb[k] = ld16(s + hoff + k*64);
      wvm0();
      for (;;) {
        unsigned bad = 0;
        #pragma unroll
        for (int k = 0; k < 8; ++k) {
          const u32x4 d = (hb[k] ^ pat) & 0x00010001u;
          bad |= d[0] | d[1] | d[2] | d[3];
        }
        if (__all(bad == 0)) break;
        #pragma unroll
        for (int k = 0; k < 8; ++k) hb[k] = ld16(s + hoff + k*64);
        wvm0();
      }
      #pragma unroll
      for (int q = 0; q < 4; ++q) acc[q] = (f32x4){0.f, 0.f, 0.f, 0.f};
      #pragma unroll
      for (int kt = 0; kt < 8; ++kt) {
        const f16x8 A = __builtin_bit_cast(f16x8, hb[kt]);
        #pragma unroll
        for (int q = 0; q < 4; ++q)
          acc[q] = __builtin_amdgcn_mfma_f32_16x16x32_f16(A, W0[q][kt], acc[q], 0, 0, 0);
      }
      #pragma unroll
      for (int q = 0; q < 4; ++q) xch[hf*4 + q][lane] = acc[q];
    }
    barrier_lds();
    if (role == 1 && p >= 1) {
      if (p >= 2) {
        #pragma unroll
        for (int q = 0; q < 4; ++q) acc[q] = acc[q] + xch[hf*4 + q][lane];
      }
      if (p < TT) {
        char* d = H1R((p - 1) & 1);
        const unsigned wt = fb_tg(p - 1);
        #pragma unroll
        for (int r = 0; r < 4; ++r) {
          const float iv = sigm(acc[0][r]), fv = sigm(acc[1][r]);
          const float gv = tanh_(acc[2][r]), ov = sigm(acc[3][r]);
          cst[r] = fv * cst[r] + iv * gv;
          const float h = ov * tanh_(cst[r]);
          unsigned short hb = __builtin_bit_cast(unsigned short, (_Float16)h);
          hb = (unsigned short)((hb & 0xFFFEu) | wt);
          st2(d + soff[r], (unsigned)hb);
        }
      } else {
        #pragma unroll
        for (int r = 0; r < 4; ++r) {
          const float iv = sigm(acc[0][r]), fv = sigm(acc[1][r]);
          const float gv = tanh_(acc[2][r]), ov = sigm(acc[3][r]);
          cst[r] = fv * cst[r] + iv * gv;
          const float h = ov * tanh_(cst[r]);
          const int b = hf*16 + ((lane>>4)<<2) + r;
          out[(size_t)(g*32 + b) * HH + (w*16 + col16)] = h;
        }
      }
    }
  }
  #undef H0R
  #undef H1R
}

extern "C" void kernel_launch(void* const* d_in, const int* in_sizes, int n_in,
                              void* d_out, int out_size, void* d_ws, size_t ws_size,
                              hipStream_t stream) {
  (void)in_sizes; (void)n_in; (void)out_size;
  const float* M    = (const float*)d_in[0];
  const float* Wih0 = (const float*)d_in[1];
  const float* Whh0 = (const float*)d_in[2];
  const float* bih0 = (const float*)d_in[3];
  const float* bhh0 = (const float*)d_in[4];
  const float* Wih1 = (const float*)d_in[5];
  const float* Whh1 = (const float*)d_in[6];
  const float* bih1 = (const float*)d_in[7];
  const float* bhh1 = (const float*)d_in[8];

  if (ws_size >= (size_t)16 * GS) {
    const int n16 = 16 * (GS / 16);
    init_ws<<<(n16 + 255) / 256, 256, 0, stream>>>((uint4*)d_ws, n16);
    lstm_v16<<<192, 256, 0, stream>>>(M, Wih0, Whh0, bih0, bhh0,
                                      Wih1, Whh1, bih1, bhh1,
                                      (float*)d_out, (char*)d_ws);
  } else {
    if (ws_size < 524288) return;
    fb_init<<<128, 256, 0, stream>>>((uint4*)d_ws, 32768);
    lstm_v9<<<128, 512, 0, stream>>>(M, Wih0, Whh0, bih0, bhh0,
                                     Wih1, Whh1, bih1, bhh1,
                                     (float*)d_out, (char*)d_ws);
  }
}